// Round 1
// baseline (3047.250 us; speedup 1.0000x reference)
//
#include <hip/hip_runtime.h>
#include <hip/hip_bf16.h>
#include <math.h>

// GCN link predictor: N=100000 nodes, d=128, E=1.6M edges, EL=200K label edges.
// Pipeline:
//   deg -> dinv (shared by both layers)
//   h1 = x @ W1            (fp32 GEMM, W in LDS)
//   z1 = relu(scatter(h1) + b1)
//   h2 = z1 @ W2
//   z2 = scatter(h2) + b2
//   logits[e] = dot(z2[s_e], z2[d_e])
// Scatter = self-loop init (agg = h*dinv^2) + per-edge wave atomics.
// Workspace: [dinv: N floats][bufH: N*128 floats][bufZ: N*128 floats] ~104 MB.

#define WAVE 64

__global__ __launch_bounds__(256) void deg_init_kern(float* deg, int N) {
    int i = blockIdx.x * blockDim.x + threadIdx.x;
    if (i < N) deg[i] = 1.0f;  // self-loop
}

__global__ __launch_bounds__(256) void deg_count_kern(const int* __restrict__ dst, float* deg, int E) {
    int i = blockIdx.x * blockDim.x + threadIdx.x;
    if (i < E) atomicAdd(&deg[dst[i]], 1.0f);
}

__global__ __launch_bounds__(256) void dinv_kern(float* deg_dinv, int N) {
    int i = blockIdx.x * blockDim.x + threadIdx.x;
    if (i < N) deg_dinv[i] = 1.0f / sqrtf(deg_dinv[i]);
}

// H[M,128] = X[M,128] @ W[128,128], fp32. One block: 64 rows x 128 cols.
// 256 threads, each 8 rows x 4 cols (float4 acc). W + X tile staged in LDS (96 KB).
__global__ __launch_bounds__(256) void gemm128_kern(const float* __restrict__ X,
                                                    const float* __restrict__ W,
                                                    float* __restrict__ H, int M) {
    __shared__ float xs[64][128];
    __shared__ float wsm[128][128];
    int tid = threadIdx.x;
    int block_row = blockIdx.x * 64;

    const float4* W4 = (const float4*)W;
    float4* ws4 = (float4*)wsm;
#pragma unroll
    for (int i = 0; i < 16; ++i) ws4[tid + 256 * i] = W4[tid + 256 * i];

#pragma unroll
    for (int i = 0; i < 8; ++i) {
        int idx = tid + 256 * i;      // float4 index in 64x32 tile
        int r = idx >> 5;
        int c = idx & 31;
        int grow = block_row + r;
        float4 v = make_float4(0.f, 0.f, 0.f, 0.f);
        if (grow < M) v = ((const float4*)X)[(size_t)grow * 32 + c];
        ((float4*)xs)[idx] = v;
    }
    __syncthreads();

    int tx = tid & 31;   // col group: cols [tx*4, tx*4+3]
    int ty = tid >> 5;   // row group: rows [ty*8, ty*8+7]
    float4 acc[8];
#pragma unroll
    for (int i = 0; i < 8; ++i) acc[i] = make_float4(0.f, 0.f, 0.f, 0.f);

#pragma unroll 4
    for (int k = 0; k < 128; ++k) {
        float4 wv = ((float4*)&wsm[k][0])[tx];
        float xr[8];
#pragma unroll
        for (int i = 0; i < 8; ++i) xr[i] = xs[ty * 8 + i][k];
#pragma unroll
        for (int i = 0; i < 8; ++i) {
            acc[i].x = fmaf(xr[i], wv.x, acc[i].x);
            acc[i].y = fmaf(xr[i], wv.y, acc[i].y);
            acc[i].z = fmaf(xr[i], wv.z, acc[i].z);
            acc[i].w = fmaf(xr[i], wv.w, acc[i].w);
        }
    }

#pragma unroll
    for (int i = 0; i < 8; ++i) {
        int grow = block_row + ty * 8 + i;
        if (grow < M) ((float4*)H)[(size_t)grow * 32 + tx] = acc[i];
    }
}

// agg[v] = h[v] * dinv[v]^2  (self-loop term), full overwrite (d_ws is poisoned).
__global__ __launch_bounds__(256) void agg_init_kern(const float* __restrict__ h,
                                                     const float* __restrict__ dinv,
                                                     float* __restrict__ agg, int N) {
    int i = blockIdx.x * blockDim.x + threadIdx.x;  // float4 index
    int total = N * 32;
    if (i >= total) return;
    int v = i >> 5;
    float s = dinv[v];
    s = s * s;
    float4 hv = ((const float4*)h)[i];
    hv.x *= s; hv.y *= s; hv.z *= s; hv.w *= s;
    ((float4*)agg)[i] = hv;
}

// One wave per edge: agg[dst] += h[src] * dinv[src]*dinv[dst]
__global__ __launch_bounds__(256) void scatter_kern(const int* __restrict__ src,
                                                    const int* __restrict__ dst,
                                                    const float* __restrict__ dinv,
                                                    const float* __restrict__ h,
                                                    float* __restrict__ agg, int E) {
    int lane = threadIdx.x & (WAVE - 1);
    int wave = (blockIdx.x * blockDim.x + threadIdx.x) >> 6;
    if (wave >= E) return;
    int s = src[wave];
    int d = dst[wave];
    float norm = dinv[s] * dinv[d];
    float2 v = ((const float2*)(h + (size_t)s * 128))[lane];
    float* ad = agg + (size_t)d * 128 + lane * 2;
    atomicAdd(ad, v.x * norm);
    atomicAdd(ad + 1, v.y * norm);
}

// z = (relu?) (agg + b), in place on agg.
__global__ __launch_bounds__(256) void bias_act_kern(float* __restrict__ agg,
                                                     const float* __restrict__ b,
                                                     int N, int do_relu) {
    int i = blockIdx.x * blockDim.x + threadIdx.x;  // float4 index
    int total = N * 32;
    if (i >= total) return;
    int c4 = i & 31;
    float4 bv = ((const float4*)b)[c4];
    float4 v = ((float4*)agg)[i];
    v.x += bv.x; v.y += bv.y; v.z += bv.z; v.w += bv.w;
    if (do_relu) {
        v.x = fmaxf(v.x, 0.f); v.y = fmaxf(v.y, 0.f);
        v.z = fmaxf(v.z, 0.f); v.w = fmaxf(v.w, 0.f);
    }
    ((float4*)agg)[i] = v;
}

// One wave per label edge: out[e] = dot(z[s], z[d]) over 128 dims.
__global__ __launch_bounds__(256) void decode_kern(const int* __restrict__ s_idx,
                                                   const int* __restrict__ d_idx,
                                                   const float* __restrict__ z,
                                                   float* __restrict__ out, int EL) {
    int lane = threadIdx.x & (WAVE - 1);
    int wave = (blockIdx.x * blockDim.x + threadIdx.x) >> 6;
    if (wave >= EL) return;
    int s = s_idx[wave];
    int d = d_idx[wave];
    float2 a = ((const float2*)(z + (size_t)s * 128))[lane];
    float2 b = ((const float2*)(z + (size_t)d * 128))[lane];
    float p = a.x * b.x + a.y * b.y;
#pragma unroll
    for (int off = 32; off > 0; off >>= 1) p += __shfl_down(p, off, 64);
    if (lane == 0) out[wave] = p;
}

extern "C" void kernel_launch(void* const* d_in, const int* in_sizes, int n_in,
                              void* d_out, int out_size, void* d_ws, size_t ws_size,
                              hipStream_t stream) {
    const float* x  = (const float*)d_in[0];
    const int*   ei = (const int*)d_in[1];
    const int*   eli = (const int*)d_in[2];
    const float* W1 = (const float*)d_in[3];
    const float* b1 = (const float*)d_in[4];
    const float* W2 = (const float*)d_in[5];
    const float* b2 = (const float*)d_in[6];
    float* out = (float*)d_out;

    int N  = in_sizes[0] / 128;
    int E  = in_sizes[1] / 2;
    int EL = in_sizes[2] / 2;
    const int* src = ei;
    const int* dst = ei + E;
    const int* ls  = eli;
    const int* ld  = eli + EL;

    char* ws = (char*)d_ws;
    size_t featBytes = (size_t)N * 128 * sizeof(float);
    float* dinv = (float*)ws;
    float* bufH = (float*)(ws + (1 << 20));
    float* bufZ = (float*)(ws + (1 << 20) + featBytes);

    int nVec4 = N * 32;  // float4 count of a feature buffer

    // degree + dinv (shared by both layers)
    deg_init_kern<<<(N + 255) / 256, 256, 0, stream>>>(dinv, N);
    deg_count_kern<<<(E + 255) / 256, 256, 0, stream>>>(dst, dinv, E);
    dinv_kern<<<(N + 255) / 256, 256, 0, stream>>>(dinv, N);

    int gemmGrid = (N + 63) / 64;
    int vecGrid  = (nVec4 + 255) / 256;
    int edgeGrid = (E + 3) / 4;   // 4 waves/block, 1 wave/edge

    // layer 1
    gemm128_kern<<<gemmGrid, 256, 0, stream>>>(x, W1, bufH, N);
    agg_init_kern<<<vecGrid, 256, 0, stream>>>(bufH, dinv, bufZ, N);
    scatter_kern<<<edgeGrid, 256, 0, stream>>>(src, dst, dinv, bufH, bufZ, E);
    bias_act_kern<<<vecGrid, 256, 0, stream>>>(bufZ, b1, N, 1);

    // layer 2
    gemm128_kern<<<gemmGrid, 256, 0, stream>>>(bufZ, W2, bufH, N);
    agg_init_kern<<<vecGrid, 256, 0, stream>>>(bufH, dinv, bufZ, N);
    scatter_kern<<<edgeGrid, 256, 0, stream>>>(src, dst, dinv, bufH, bufZ, E);
    bias_act_kern<<<vecGrid, 256, 0, stream>>>(bufZ, b2, N, 0);

    // decode
    decode_kern<<<(EL + 3) / 4, 256, 0, stream>>>(ls, ld, bufZ, out, EL);
}

// Round 2
// 899.640 us; speedup vs baseline: 3.3872x; 3.3872x over previous
//
#include <hip/hip_runtime.h>
#include <hip/hip_bf16.h>
#include <math.h>

// GCN link predictor: N=100000 nodes, d=128, E=1.6M edges, EL=200K label edges.
// Round 2: replace atomic scatter (410M fp32 atomics, 2x1299us) with on-device
// CSR build + gather aggregation (one wave per node, register accumulate,
// single write per output row). CSR stores int2{src, norm} so the agg inner
// loop has a 1-deep load chain.
//
// Workspace layout (bytes):
//   0        dinv    float[N]     (400 KB)
//   512K     deg     int[N]       (400 KB)
//   1024K    row_off int[N+1]     (400 KB)
//   1536K    cursor  int[N]       (400 KB)
//   2048K    csr     int2[E]      (12.8 MB)
//   16M      bufH    float[N*128] (51.2 MB)
//   16M+51.2M bufZ   float[N*128] (51.2 MB)   total ~113.7 MiB

#define WAVE 64

__global__ __launch_bounds__(256) void zero2_kern(int* __restrict__ a,
                                                  int* __restrict__ b, int N) {
    int i = blockIdx.x * blockDim.x + threadIdx.x;
    if (i < N) { a[i] = 0; b[i] = 0; }
}

__global__ __launch_bounds__(256) void deg_count_kern(const int* __restrict__ dst,
                                                      int* __restrict__ deg, int E) {
    int i = blockIdx.x * blockDim.x + threadIdx.x;
    if (i < E) atomicAdd(&deg[dst[i]], 1);
}

// Single-block exclusive scan of deg -> row_off, plus dinv = rsqrt(deg+1).
__global__ __launch_bounds__(1024) void scan_kern(const int* __restrict__ deg,
                                                  int* __restrict__ row_off,
                                                  float* __restrict__ dinv, int N) {
    __shared__ int sdata[1024];
    int t = threadIdx.x;
    int C = (N + 1023) / 1024;
    int lo = t * C;
    int hi = lo + C; if (hi > N) hi = N;
    int sum = 0;
    for (int i = lo; i < hi; ++i) sum += deg[i];
    sdata[t] = sum;
    __syncthreads();
    for (int off = 1; off < 1024; off <<= 1) {
        int v = sdata[t];
        int add = (t >= off) ? sdata[t - off] : 0;
        __syncthreads();
        sdata[t] = v + add;
        __syncthreads();
    }
    int run = sdata[t] - sum;  // exclusive prefix of this thread's chunk
    for (int i = lo; i < hi; ++i) {
        int d = deg[i];
        row_off[i] = run;
        dinv[i] = rsqrtf((float)(d + 1));  // +1 self-loop
        run += d;
    }
    if (t == 1023) row_off[N] = sdata[1023];
}

// csr[row_off[dst]+slot] = {src, norm}. Order within a node is arbitrary (fp
// sum order nondeterminism is within validation threshold).
__global__ __launch_bounds__(256) void fill_kern(const int* __restrict__ src,
                                                 const int* __restrict__ dst,
                                                 const int* __restrict__ row_off,
                                                 int* __restrict__ cursor,
                                                 const float* __restrict__ dinv,
                                                 int2* __restrict__ csr, int E) {
    int e = blockIdx.x * blockDim.x + threadIdx.x;
    if (e >= E) return;
    int s = src[e], d = dst[e];
    int p = atomicAdd(&cursor[d], 1);
    int2 v;
    v.x = s;
    v.y = __float_as_int(dinv[s] * dinv[d]);
    csr[row_off[d] + p] = v;
}

// H[M,128] = X[M,128] @ W[128,128], fp32. One block: 64 rows x 128 cols.
__global__ __launch_bounds__(256) void gemm128_kern(const float* __restrict__ X,
                                                    const float* __restrict__ W,
                                                    float* __restrict__ H, int M) {
    __shared__ float xs[64][128];
    __shared__ float wsm[128][128];
    int tid = threadIdx.x;
    int block_row = blockIdx.x * 64;

    const float4* W4 = (const float4*)W;
    float4* ws4 = (float4*)wsm;
#pragma unroll
    for (int i = 0; i < 16; ++i) ws4[tid + 256 * i] = W4[tid + 256 * i];

#pragma unroll
    for (int i = 0; i < 8; ++i) {
        int idx = tid + 256 * i;  // float4 index in 64x32 tile
        int r = idx >> 5;
        int c = idx & 31;
        int grow = block_row + r;
        float4 v = make_float4(0.f, 0.f, 0.f, 0.f);
        if (grow < M) v = ((const float4*)X)[(size_t)grow * 32 + c];
        ((float4*)xs)[idx] = v;
    }
    __syncthreads();

    int tx = tid & 31;
    int ty = tid >> 5;
    float4 acc[8];
#pragma unroll
    for (int i = 0; i < 8; ++i) acc[i] = make_float4(0.f, 0.f, 0.f, 0.f);

#pragma unroll 4
    for (int k = 0; k < 128; ++k) {
        float4 wv = ((float4*)&wsm[k][0])[tx];
        float xr[8];
#pragma unroll
        for (int i = 0; i < 8; ++i) xr[i] = xs[ty * 8 + i][k];
#pragma unroll
        for (int i = 0; i < 8; ++i) {
            acc[i].x = fmaf(xr[i], wv.x, acc[i].x);
            acc[i].y = fmaf(xr[i], wv.y, acc[i].y);
            acc[i].z = fmaf(xr[i], wv.z, acc[i].z);
            acc[i].w = fmaf(xr[i], wv.w, acc[i].w);
        }
    }

#pragma unroll
    for (int i = 0; i < 8; ++i) {
        int grow = block_row + ty * 8 + i;
        if (grow < M) ((float4*)H)[(size_t)grow * 32 + tx] = acc[i];
    }
}

// One wave per node: z[v] = (relu?)(sum_{s in N(v)} h[s]*norm + h[v]*dinv^2 + b)
__global__ __launch_bounds__(256) void agg_kern(const int* __restrict__ row_off,
                                                const int2* __restrict__ csr,
                                                const float* __restrict__ dinv,
                                                const float* __restrict__ h,
                                                const float* __restrict__ bias,
                                                float* __restrict__ z,
                                                int N, int do_relu) {
    int wave = (blockIdx.x * blockDim.x + threadIdx.x) >> 6;
    int lane = threadIdx.x & (WAVE - 1);
    if (wave >= N) return;
    int v = wave;
    float dv = dinv[v];
    int beg = row_off[v];
    int degv = row_off[v + 1] - beg;

    float2 acc = ((const float2*)(h + (size_t)v * 128))[lane];
    float ss = dv * dv;
    acc.x *= ss; acc.y *= ss;

    for (int base = 0; base < degv; base += WAVE) {
        int cnt = degv - base; if (cnt > WAVE) cnt = WAVE;
        int2 my = make_int2(0, 0);
        if (lane < cnt) my = csr[beg + base + lane];  // coalesced edge read
        int j = 0;
        for (; j + 4 <= cnt; j += 4) {
            int   s0 = __shfl(my.x, j + 0); float n0 = __int_as_float(__shfl(my.y, j + 0));
            int   s1 = __shfl(my.x, j + 1); float n1 = __int_as_float(__shfl(my.y, j + 1));
            int   s2 = __shfl(my.x, j + 2); float n2 = __int_as_float(__shfl(my.y, j + 2));
            int   s3 = __shfl(my.x, j + 3); float n3 = __int_as_float(__shfl(my.y, j + 3));
            float2 h0 = ((const float2*)(h + (size_t)s0 * 128))[lane];
            float2 h1 = ((const float2*)(h + (size_t)s1 * 128))[lane];
            float2 h2 = ((const float2*)(h + (size_t)s2 * 128))[lane];
            float2 h3 = ((const float2*)(h + (size_t)s3 * 128))[lane];
            acc.x = fmaf(h0.x, n0, acc.x); acc.y = fmaf(h0.y, n0, acc.y);
            acc.x = fmaf(h1.x, n1, acc.x); acc.y = fmaf(h1.y, n1, acc.y);
            acc.x = fmaf(h2.x, n2, acc.x); acc.y = fmaf(h2.y, n2, acc.y);
            acc.x = fmaf(h3.x, n3, acc.x); acc.y = fmaf(h3.y, n3, acc.y);
        }
        for (; j < cnt; ++j) {
            int   s0 = __shfl(my.x, j); float n0 = __int_as_float(__shfl(my.y, j));
            float2 h0 = ((const float2*)(h + (size_t)s0 * 128))[lane];
            acc.x = fmaf(h0.x, n0, acc.x); acc.y = fmaf(h0.y, n0, acc.y);
        }
    }

    float2 bv = ((const float2*)bias)[lane];
    acc.x += bv.x; acc.y += bv.y;
    if (do_relu) { acc.x = fmaxf(acc.x, 0.f); acc.y = fmaxf(acc.y, 0.f); }
    ((float2*)(z + (size_t)v * 128))[lane] = acc;
}

// One wave per label edge: out[e] = dot(z[s], z[d]) over 128 dims.
__global__ __launch_bounds__(256) void decode_kern(const int* __restrict__ s_idx,
                                                   const int* __restrict__ d_idx,
                                                   const float* __restrict__ z,
                                                   float* __restrict__ out, int EL) {
    int lane = threadIdx.x & (WAVE - 1);
    int wave = (blockIdx.x * blockDim.x + threadIdx.x) >> 6;
    if (wave >= EL) return;
    int s = s_idx[wave];
    int d = d_idx[wave];
    float2 a = ((const float2*)(z + (size_t)s * 128))[lane];
    float2 b = ((const float2*)(z + (size_t)d * 128))[lane];
    float p = a.x * b.x + a.y * b.y;
#pragma unroll
    for (int off = 32; off > 0; off >>= 1) p += __shfl_down(p, off, 64);
    if (lane == 0) out[wave] = p;
}

extern "C" void kernel_launch(void* const* d_in, const int* in_sizes, int n_in,
                              void* d_out, int out_size, void* d_ws, size_t ws_size,
                              hipStream_t stream) {
    const float* x   = (const float*)d_in[0];
    const int*   ei  = (const int*)d_in[1];
    const int*   eli = (const int*)d_in[2];
    const float* W1  = (const float*)d_in[3];
    const float* b1  = (const float*)d_in[4];
    const float* W2  = (const float*)d_in[5];
    const float* b2  = (const float*)d_in[6];
    float* out = (float*)d_out;

    int N  = in_sizes[0] / 128;
    int E  = in_sizes[1] / 2;
    int EL = in_sizes[2] / 2;
    const int* src = ei;
    const int* dst = ei + E;
    const int* ls  = eli;
    const int* ld  = eli + EL;

    char* ws = (char*)d_ws;
    float* dinv    = (float*)(ws);
    int*   deg     = (int*)(ws + (512 << 10));
    int*   row_off = (int*)(ws + (1024 << 10));
    int*   cursor  = (int*)(ws + (1536 << 10));
    int2*  csr     = (int2*)(ws + (2048 << 10));
    float* bufH    = (float*)(ws + (16u << 20));
    float* bufZ    = (float*)(ws + (16u << 20) + (size_t)51200000u);

    int nodeGrid = (N + 255) / 256;
    int edgeGrid = (E + 255) / 256;
    int gemmGrid = (N + 63) / 64;
    int aggGrid  = (N + 3) / 4;   // 4 waves/block, 1 wave/node

    // CSR build (shared by both layers)
    zero2_kern<<<nodeGrid, 256, 0, stream>>>(deg, cursor, N);
    deg_count_kern<<<edgeGrid, 256, 0, stream>>>(dst, deg, E);
    scan_kern<<<1, 1024, 0, stream>>>(deg, row_off, dinv, N);
    fill_kern<<<edgeGrid, 256, 0, stream>>>(src, dst, row_off, cursor, dinv, csr, E);

    // layer 1
    gemm128_kern<<<gemmGrid, 256, 0, stream>>>(x, W1, bufH, N);
    agg_kern<<<aggGrid, 256, 0, stream>>>(row_off, csr, dinv, bufH, b1, bufZ, N, 1);

    // layer 2
    gemm128_kern<<<gemmGrid, 256, 0, stream>>>(bufZ, W2, bufH, N);
    agg_kern<<<aggGrid, 256, 0, stream>>>(row_off, csr, dinv, bufH, b2, bufZ, N, 0);

    // decode
    decode_kern<<<(EL + 3) / 4, 256, 0, stream>>>(ls, ld, bufZ, out, EL);
}

// Round 3
// 687.810 us; speedup vs baseline: 4.4304x; 1.3080x over previous
//
#include <hip/hip_runtime.h>
#include <hip/hip_bf16.h>
#include <math.h>

// GCN link predictor: N=100000 nodes, d=128, E=1.6M edges, EL=200K label edges.
// Round 3: single-block scan (230us, 1 CU latency-bound) -> 3-kernel
// hierarchical scan (scan_part / scan_top / scan_apply), all device-parallel.
//
// Workspace layout (bytes):
//   0        dinv    float[N]     (400 KB)
//   512K     deg     int[N]       (400 KB)
//   1024K    row_off int[N+1]     (400 KB)
//   1536K    cursor  int[N]       (400 KB)
//   1984K    bsum    int[128]
//   2048K    csr     int2[E]      (12.8 MB)
//   16M      bufH    float[N*128] (51.2 MB)
//   16M+51.2M bufZ   float[N*128] (51.2 MB)   total ~113.7 MiB

#define WAVE 64
#define SCAN_CHUNK 1024   // elements per block (256 threads x 4)

__global__ __launch_bounds__(256) void zero2_kern(int* __restrict__ a,
                                                  int* __restrict__ b, int N) {
    int i = blockIdx.x * blockDim.x + threadIdx.x;
    if (i < N) { a[i] = 0; b[i] = 0; }
}

__global__ __launch_bounds__(256) void deg_count_kern(const int* __restrict__ dst,
                                                      int* __restrict__ deg, int E) {
    int i = blockIdx.x * blockDim.x + threadIdx.x;
    if (i < E) atomicAdd(&deg[dst[i]], 1);
}

__device__ __forceinline__ int load4_sum(const int* __restrict__ deg, int base, int N,
                                         int4* out) {
    int4 v = make_int4(0, 0, 0, 0);
    if (base + 3 < N) {
        v = ((const int4*)deg)[base >> 2];
    } else {
        if (base + 0 < N) v.x = deg[base + 0];
        if (base + 1 < N) v.y = deg[base + 1];
        if (base + 2 < N) v.z = deg[base + 2];
        if (base + 3 < N) v.w = deg[base + 3];
    }
    *out = v;
    return v.x + v.y + v.z + v.w;
}

// Per-block partial sums of deg.
__global__ __launch_bounds__(256) void scan_part_kern(const int* __restrict__ deg,
                                                      int* __restrict__ bsum, int N) {
    __shared__ int sdata[256];
    int t = threadIdx.x;
    int base = blockIdx.x * SCAN_CHUNK + t * 4;
    int4 v;
    int sum = load4_sum(deg, base, N, &v);
    sdata[t] = sum;
    __syncthreads();
#pragma unroll
    for (int off = 128; off > 0; off >>= 1) {
        if (t < off) sdata[t] += sdata[t + off];
        __syncthreads();
    }
    if (t == 0) bsum[blockIdx.x] = sdata[0];
}

// Single small block: exclusive scan of nb (<=128) block sums; row_off[N]=total.
__global__ __launch_bounds__(128) void scan_top_kern(int* __restrict__ bsum,
                                                     int* __restrict__ row_off,
                                                     int nb, int N) {
    __shared__ int sdata[128];
    int t = threadIdx.x;
    int own = (t < nb) ? bsum[t] : 0;
    sdata[t] = own;
    __syncthreads();
#pragma unroll
    for (int off = 1; off < 128; off <<= 1) {
        int v = sdata[t];
        int add = (t >= off) ? sdata[t - off] : 0;
        __syncthreads();
        sdata[t] = v + add;
        __syncthreads();
    }
    if (t < nb) bsum[t] = sdata[t] - own;   // exclusive
    if (t == 127) row_off[N] = sdata[127];  // total == E
}

// Re-scan locally, add block offset, write row_off + dinv.
__global__ __launch_bounds__(256) void scan_apply_kern(const int* __restrict__ deg,
                                                       const int* __restrict__ bsum,
                                                       int* __restrict__ row_off,
                                                       float* __restrict__ dinv, int N) {
    __shared__ int sdata[256];
    int t = threadIdx.x;
    int base = blockIdx.x * SCAN_CHUNK + t * 4;
    int4 v;
    int sum = load4_sum(deg, base, N, &v);
    sdata[t] = sum;
    __syncthreads();
#pragma unroll
    for (int off = 1; off < 256; off <<= 1) {
        int x = sdata[t];
        int add = (t >= off) ? sdata[t - off] : 0;
        __syncthreads();
        sdata[t] = x + add;
        __syncthreads();
    }
    int run = bsum[blockIdx.x] + sdata[t] - sum;  // global exclusive prefix
    if (base + 0 < N) { row_off[base + 0] = run; dinv[base + 0] = rsqrtf((float)(v.x + 1)); run += v.x; }
    if (base + 1 < N) { row_off[base + 1] = run; dinv[base + 1] = rsqrtf((float)(v.y + 1)); run += v.y; }
    if (base + 2 < N) { row_off[base + 2] = run; dinv[base + 2] = rsqrtf((float)(v.z + 1)); run += v.z; }
    if (base + 3 < N) { row_off[base + 3] = run; dinv[base + 3] = rsqrtf((float)(v.w + 1)); }
}

// csr[row_off[dst]+slot] = {src, norm}.
__global__ __launch_bounds__(256) void fill_kern(const int* __restrict__ src,
                                                 const int* __restrict__ dst,
                                                 const int* __restrict__ row_off,
                                                 int* __restrict__ cursor,
                                                 const float* __restrict__ dinv,
                                                 int2* __restrict__ csr, int E) {
    int e = blockIdx.x * blockDim.x + threadIdx.x;
    if (e >= E) return;
    int s = src[e], d = dst[e];
    int p = atomicAdd(&cursor[d], 1);
    int2 v;
    v.x = s;
    v.y = __float_as_int(dinv[s] * dinv[d]);
    csr[row_off[d] + p] = v;
}

// H[M,128] = X[M,128] @ W[128,128], fp32. One block: 64 rows x 128 cols.
__global__ __launch_bounds__(256) void gemm128_kern(const float* __restrict__ X,
                                                    const float* __restrict__ W,
                                                    float* __restrict__ H, int M) {
    __shared__ float xs[64][128];
    __shared__ float wsm[128][128];
    int tid = threadIdx.x;
    int block_row = blockIdx.x * 64;

    const float4* W4 = (const float4*)W;
    float4* ws4 = (float4*)wsm;
#pragma unroll
    for (int i = 0; i < 16; ++i) ws4[tid + 256 * i] = W4[tid + 256 * i];

#pragma unroll
    for (int i = 0; i < 8; ++i) {
        int idx = tid + 256 * i;  // float4 index in 64x32 tile
        int r = idx >> 5;
        int c = idx & 31;
        int grow = block_row + r;
        float4 v = make_float4(0.f, 0.f, 0.f, 0.f);
        if (grow < M) v = ((const float4*)X)[(size_t)grow * 32 + c];
        ((float4*)xs)[idx] = v;
    }
    __syncthreads();

    int tx = tid & 31;
    int ty = tid >> 5;
    float4 acc[8];
#pragma unroll
    for (int i = 0; i < 8; ++i) acc[i] = make_float4(0.f, 0.f, 0.f, 0.f);

#pragma unroll 4
    for (int k = 0; k < 128; ++k) {
        float4 wv = ((float4*)&wsm[k][0])[tx];
        float xr[8];
#pragma unroll
        for (int i = 0; i < 8; ++i) xr[i] = xs[ty * 8 + i][k];
#pragma unroll
        for (int i = 0; i < 8; ++i) {
            acc[i].x = fmaf(xr[i], wv.x, acc[i].x);
            acc[i].y = fmaf(xr[i], wv.y, acc[i].y);
            acc[i].z = fmaf(xr[i], wv.z, acc[i].z);
            acc[i].w = fmaf(xr[i], wv.w, acc[i].w);
        }
    }

#pragma unroll
    for (int i = 0; i < 8; ++i) {
        int grow = block_row + ty * 8 + i;
        if (grow < M) ((float4*)H)[(size_t)grow * 32 + tx] = acc[i];
    }
}

// One wave per node: z[v] = (relu?)(sum_{s in N(v)} h[s]*norm + h[v]*dinv^2 + b)
__global__ __launch_bounds__(256) void agg_kern(const int* __restrict__ row_off,
                                                const int2* __restrict__ csr,
                                                const float* __restrict__ dinv,
                                                const float* __restrict__ h,
                                                const float* __restrict__ bias,
                                                float* __restrict__ z,
                                                int N, int do_relu) {
    int wave = (blockIdx.x * blockDim.x + threadIdx.x) >> 6;
    int lane = threadIdx.x & (WAVE - 1);
    if (wave >= N) return;
    int v = wave;
    float dv = dinv[v];
    int beg = row_off[v];
    int degv = row_off[v + 1] - beg;

    float2 acc = ((const float2*)(h + (size_t)v * 128))[lane];
    float ss = dv * dv;
    acc.x *= ss; acc.y *= ss;

    for (int base = 0; base < degv; base += WAVE) {
        int cnt = degv - base; if (cnt > WAVE) cnt = WAVE;
        int2 my = make_int2(0, 0);
        if (lane < cnt) my = csr[beg + base + lane];  // coalesced edge read
        int j = 0;
        for (; j + 4 <= cnt; j += 4) {
            int   s0 = __shfl(my.x, j + 0); float n0 = __int_as_float(__shfl(my.y, j + 0));
            int   s1 = __shfl(my.x, j + 1); float n1 = __int_as_float(__shfl(my.y, j + 1));
            int   s2 = __shfl(my.x, j + 2); float n2 = __int_as_float(__shfl(my.y, j + 2));
            int   s3 = __shfl(my.x, j + 3); float n3 = __int_as_float(__shfl(my.y, j + 3));
            float2 h0 = ((const float2*)(h + (size_t)s0 * 128))[lane];
            float2 h1 = ((const float2*)(h + (size_t)s1 * 128))[lane];
            float2 h2 = ((const float2*)(h + (size_t)s2 * 128))[lane];
            float2 h3 = ((const float2*)(h + (size_t)s3 * 128))[lane];
            acc.x = fmaf(h0.x, n0, acc.x); acc.y = fmaf(h0.y, n0, acc.y);
            acc.x = fmaf(h1.x, n1, acc.x); acc.y = fmaf(h1.y, n1, acc.y);
            acc.x = fmaf(h2.x, n2, acc.x); acc.y = fmaf(h2.y, n2, acc.y);
            acc.x = fmaf(h3.x, n3, acc.x); acc.y = fmaf(h3.y, n3, acc.y);
        }
        for (; j < cnt; ++j) {
            int   s0 = __shfl(my.x, j); float n0 = __int_as_float(__shfl(my.y, j));
            float2 h0 = ((const float2*)(h + (size_t)s0 * 128))[lane];
            acc.x = fmaf(h0.x, n0, acc.x); acc.y = fmaf(h0.y, n0, acc.y);
        }
    }

    float2 bv = ((const float2*)bias)[lane];
    acc.x += bv.x; acc.y += bv.y;
    if (do_relu) { acc.x = fmaxf(acc.x, 0.f); acc.y = fmaxf(acc.y, 0.f); }
    ((float2*)(z + (size_t)v * 128))[lane] = acc;
}

// One wave per label edge: out[e] = dot(z[s], z[d]) over 128 dims.
__global__ __launch_bounds__(256) void decode_kern(const int* __restrict__ s_idx,
                                                   const int* __restrict__ d_idx,
                                                   const float* __restrict__ z,
                                                   float* __restrict__ out, int EL) {
    int lane = threadIdx.x & (WAVE - 1);
    int wave = (blockIdx.x * blockDim.x + threadIdx.x) >> 6;
    if (wave >= EL) return;
    int s = s_idx[wave];
    int d = d_idx[wave];
    float2 a = ((const float2*)(z + (size_t)s * 128))[lane];
    float2 b = ((const float2*)(z + (size_t)d * 128))[lane];
    float p = a.x * b.x + a.y * b.y;
#pragma unroll
    for (int off = 32; off > 0; off >>= 1) p += __shfl_down(p, off, 64);
    if (lane == 0) out[wave] = p;
}

extern "C" void kernel_launch(void* const* d_in, const int* in_sizes, int n_in,
                              void* d_out, int out_size, void* d_ws, size_t ws_size,
                              hipStream_t stream) {
    const float* x   = (const float*)d_in[0];
    const int*   ei  = (const int*)d_in[1];
    const int*   eli = (const int*)d_in[2];
    const float* W1  = (const float*)d_in[3];
    const float* b1  = (const float*)d_in[4];
    const float* W2  = (const float*)d_in[5];
    const float* b2  = (const float*)d_in[6];
    float* out = (float*)d_out;

    int N  = in_sizes[0] / 128;
    int E  = in_sizes[1] / 2;
    int EL = in_sizes[2] / 2;
    const int* src = ei;
    const int* dst = ei + E;
    const int* ls  = eli;
    const int* ld  = eli + EL;

    char* ws = (char*)d_ws;
    float* dinv    = (float*)(ws);
    int*   deg     = (int*)(ws + (512 << 10));
    int*   row_off = (int*)(ws + (1024 << 10));
    int*   cursor  = (int*)(ws + (1536 << 10));
    int*   bsum    = (int*)(ws + (1984 << 10));
    int2*  csr     = (int2*)(ws + (2048 << 10));
    float* bufH    = (float*)(ws + (16u << 20));
    float* bufZ    = (float*)(ws + (16u << 20) + (size_t)51200000u);

    int nodeGrid = (N + 255) / 256;
    int edgeGrid = (E + 255) / 256;
    int gemmGrid = (N + 63) / 64;
    int aggGrid  = (N + 3) / 4;   // 4 waves/block, 1 wave/node
    int nbScan   = (N + SCAN_CHUNK - 1) / SCAN_CHUNK;  // 98 for N=100K (<=128)

    // CSR build (shared by both layers)
    zero2_kern<<<nodeGrid, 256, 0, stream>>>(deg, cursor, N);
    deg_count_kern<<<edgeGrid, 256, 0, stream>>>(dst, deg, E);
    scan_part_kern<<<nbScan, 256, 0, stream>>>(deg, bsum, N);
    scan_top_kern<<<1, 128, 0, stream>>>(bsum, row_off, nbScan, N);
    scan_apply_kern<<<nbScan, 256, 0, stream>>>(deg, bsum, row_off, dinv, N);
    fill_kern<<<edgeGrid, 256, 0, stream>>>(src, dst, row_off, cursor, dinv, csr, E);

    // layer 1
    gemm128_kern<<<gemmGrid, 256, 0, stream>>>(x, W1, bufH, N);
    agg_kern<<<aggGrid, 256, 0, stream>>>(row_off, csr, dinv, bufH, b1, bufZ, N, 1);

    // layer 2
    gemm128_kern<<<gemmGrid, 256, 0, stream>>>(bufZ, W2, bufH, N);
    agg_kern<<<aggGrid, 256, 0, stream>>>(row_off, csr, dinv, bufH, b2, bufZ, N, 0);

    // decode
    decode_kern<<<(EL + 3) / 4, 256, 0, stream>>>(ls, ld, bufZ, out, EL);
}

// Round 4
// 607.435 us; speedup vs baseline: 5.0166x; 1.1323x over previous
//
#include <hip/hip_runtime.h>
#include <hip/hip_bf16.h>
#include <math.h>

// GCN link predictor: N=100000 nodes, d=128, E=1.6M edges, EL=200K label edges.
// Round 4:
//  - gemm128: K chunked by 32 (24 KB LDS/block -> 6 blocks/CU, was 96 KB -> 1)
//  - agg: float4 half-wave gathers (1 load = 2 edge rows = 1 KB), unroll 4
//  - decode: 2 edges/wave, float4 loads, 32-lane xor reduce
//
// Workspace layout (bytes):
//   0        dinv    float[N]     (400 KB)
//   512K     deg     int[N]       (400 KB)
//   1024K    row_off int[N+1]     (400 KB)
//   1536K    cursor  int[N]       (400 KB)
//   1984K    bsum    int[128]
//   2048K    csr     int2[E]      (12.8 MB)
//   16M      bufH    float[N*128] (51.2 MB)
//   16M+51.2M bufZ   float[N*128] (51.2 MB)   total ~113.7 MiB

#define WAVE 64
#define SCAN_CHUNK 1024   // elements per block (256 threads x 4)
#define GK 32             // gemm k-chunk

__global__ __launch_bounds__(256) void zero2_kern(int* __restrict__ a,
                                                  int* __restrict__ b, int N) {
    int i = blockIdx.x * blockDim.x + threadIdx.x;
    if (i < N) { a[i] = 0; b[i] = 0; }
}

__global__ __launch_bounds__(256) void deg_count_kern(const int* __restrict__ dst,
                                                      int* __restrict__ deg, int E) {
    int i = blockIdx.x * blockDim.x + threadIdx.x;
    if (i < E) atomicAdd(&deg[dst[i]], 1);
}

__device__ __forceinline__ int load4_sum(const int* __restrict__ deg, int base, int N,
                                         int4* out) {
    int4 v = make_int4(0, 0, 0, 0);
    if (base + 3 < N) {
        v = ((const int4*)deg)[base >> 2];
    } else {
        if (base + 0 < N) v.x = deg[base + 0];
        if (base + 1 < N) v.y = deg[base + 1];
        if (base + 2 < N) v.z = deg[base + 2];
        if (base + 3 < N) v.w = deg[base + 3];
    }
    *out = v;
    return v.x + v.y + v.z + v.w;
}

// Per-block partial sums of deg.
__global__ __launch_bounds__(256) void scan_part_kern(const int* __restrict__ deg,
                                                      int* __restrict__ bsum, int N) {
    __shared__ int sdata[256];
    int t = threadIdx.x;
    int base = blockIdx.x * SCAN_CHUNK + t * 4;
    int4 v;
    int sum = load4_sum(deg, base, N, &v);
    sdata[t] = sum;
    __syncthreads();
#pragma unroll
    for (int off = 128; off > 0; off >>= 1) {
        if (t < off) sdata[t] += sdata[t + off];
        __syncthreads();
    }
    if (t == 0) bsum[blockIdx.x] = sdata[0];
}

// Single small block: exclusive scan of nb (<=128) block sums; row_off[N]=total.
__global__ __launch_bounds__(128) void scan_top_kern(int* __restrict__ bsum,
                                                     int* __restrict__ row_off,
                                                     int nb, int N) {
    __shared__ int sdata[128];
    int t = threadIdx.x;
    int own = (t < nb) ? bsum[t] : 0;
    sdata[t] = own;
    __syncthreads();
#pragma unroll
    for (int off = 1; off < 128; off <<= 1) {
        int v = sdata[t];
        int add = (t >= off) ? sdata[t - off] : 0;
        __syncthreads();
        sdata[t] = v + add;
        __syncthreads();
    }
    if (t < nb) bsum[t] = sdata[t] - own;   // exclusive
    if (t == 127) row_off[N] = sdata[127];  // total == E
}

// Re-scan locally, add block offset, write row_off + dinv.
__global__ __launch_bounds__(256) void scan_apply_kern(const int* __restrict__ deg,
                                                       const int* __restrict__ bsum,
                                                       int* __restrict__ row_off,
                                                       float* __restrict__ dinv, int N) {
    __shared__ int sdata[256];
    int t = threadIdx.x;
    int base = blockIdx.x * SCAN_CHUNK + t * 4;
    int4 v;
    int sum = load4_sum(deg, base, N, &v);
    sdata[t] = sum;
    __syncthreads();
#pragma unroll
    for (int off = 1; off < 256; off <<= 1) {
        int x = sdata[t];
        int add = (t >= off) ? sdata[t - off] : 0;
        __syncthreads();
        sdata[t] = x + add;
        __syncthreads();
    }
    int run = bsum[blockIdx.x] + sdata[t] - sum;  // global exclusive prefix
    if (base + 0 < N) { row_off[base + 0] = run; dinv[base + 0] = rsqrtf((float)(v.x + 1)); run += v.x; }
    if (base + 1 < N) { row_off[base + 1] = run; dinv[base + 1] = rsqrtf((float)(v.y + 1)); run += v.y; }
    if (base + 2 < N) { row_off[base + 2] = run; dinv[base + 2] = rsqrtf((float)(v.z + 1)); run += v.z; }
    if (base + 3 < N) { row_off[base + 3] = run; dinv[base + 3] = rsqrtf((float)(v.w + 1)); }
}

// csr[row_off[dst]+slot] = {src, norm}.
__global__ __launch_bounds__(256) void fill_kern(const int* __restrict__ src,
                                                 const int* __restrict__ dst,
                                                 const int* __restrict__ row_off,
                                                 int* __restrict__ cursor,
                                                 const float* __restrict__ dinv,
                                                 int2* __restrict__ csr, int E) {
    int e = blockIdx.x * blockDim.x + threadIdx.x;
    if (e >= E) return;
    int s = src[e], d = dst[e];
    int p = atomicAdd(&cursor[d], 1);
    int2 v;
    v.x = s;
    v.y = __float_as_int(dinv[s] * dinv[d]);
    csr[row_off[d] + p] = v;
}

// H[M,128] = X[M,128] @ W[128,128], fp32. One block: 64 rows x 128 cols.
// K chunked by GK=32: LDS = 16 KB (W chunk) + 8 KB (X chunk) = 24 KB -> 6 blocks/CU.
__global__ __launch_bounds__(256) void gemm128_kern(const float* __restrict__ X,
                                                    const float* __restrict__ W,
                                                    float* __restrict__ H, int M) {
    __shared__ float xs[64][GK];      // 8 KB
    __shared__ float wsm[GK][128];    // 16 KB
    int tid = threadIdx.x;
    int block_row = blockIdx.x * 64;
    int tx = tid & 31;
    int ty = tid >> 5;

    float4 acc[8];
#pragma unroll
    for (int i = 0; i < 8; ++i) acc[i] = make_float4(0.f, 0.f, 0.f, 0.f);

    for (int k0 = 0; k0 < 128; k0 += GK) {
        __syncthreads();  // protect previous chunk's LDS reads
        // W chunk: GK x 128 = 1024 float4, 4/thread
        {
            const float4* W4 = (const float4*)(W + (size_t)k0 * 128);
            float4* w4 = (float4*)wsm;
#pragma unroll
            for (int i = 0; i < 4; ++i) w4[tid + 256 * i] = W4[tid + 256 * i];
        }
        // X chunk: 64 rows x GK = 512 float4, 2/thread
        {
#pragma unroll
            for (int i = 0; i < 2; ++i) {
                int idx = tid + 256 * i;   // 0..511
                int r = idx >> 3;          // 0..63
                int c = idx & 7;           // float4 within chunk
                int grow = block_row + r;
                float4 v = make_float4(0.f, 0.f, 0.f, 0.f);
                if (grow < M) v = ((const float4*)X)[(size_t)grow * 32 + (k0 >> 2) + c];
                ((float4*)xs)[idx] = v;
            }
        }
        __syncthreads();

#pragma unroll 4
        for (int kk = 0; kk < GK; ++kk) {
            float4 wv = ((float4*)&wsm[kk][0])[tx];
            float xr[8];
#pragma unroll
            for (int i = 0; i < 8; ++i) xr[i] = xs[ty * 8 + i][kk];
#pragma unroll
            for (int i = 0; i < 8; ++i) {
                acc[i].x = fmaf(xr[i], wv.x, acc[i].x);
                acc[i].y = fmaf(xr[i], wv.y, acc[i].y);
                acc[i].z = fmaf(xr[i], wv.z, acc[i].z);
                acc[i].w = fmaf(xr[i], wv.w, acc[i].w);
            }
        }
    }

#pragma unroll
    for (int i = 0; i < 8; ++i) {
        int grow = block_row + ty * 8 + i;
        if (grow < M) ((float4*)H)[(size_t)grow * 32 + tx] = acc[i];
    }
}

// One wave per node, half-wave float4 gathers (1 load instruction = 2 edge rows).
// z[v] = (relu?)(sum_{s in N(v)} h[s]*norm + h[v]*dinv^2 + b)
__global__ __launch_bounds__(256) void agg_kern(const int* __restrict__ row_off,
                                                const int2* __restrict__ csr,
                                                const float* __restrict__ dinv,
                                                const float* __restrict__ h,
                                                const float* __restrict__ bias,
                                                float* __restrict__ z,
                                                int N, int do_relu) {
    int wave = (blockIdx.x * blockDim.x + threadIdx.x) >> 6;
    int lane = threadIdx.x & (WAVE - 1);
    if (wave >= N) return;
    int v = wave;
    int half = lane >> 5;    // lanes 0-31 handle even edge slots, 32-63 odd
    int l32 = lane & 31;
    int beg = row_off[v];
    int degv = row_off[v + 1] - beg;
    const float4* h4 = (const float4*)h;

    float4 acc = make_float4(0.f, 0.f, 0.f, 0.f);

    for (int base = 0; base < degv; base += WAVE) {
        int cnt = degv - base; if (cnt > WAVE) cnt = WAVE;
        int2 my = make_int2(0, 0);  // zero => s=0, n=0 for slots beyond cnt (harmless)
        if (lane < cnt) my = csr[beg + base + lane];  // coalesced edge read
        for (int j = 0; j < cnt; j += 8) {
            int i0 = j + 0 + half, i1 = j + 2 + half, i2 = j + 4 + half, i3 = j + 6 + half;
            int   s0 = __shfl(my.x, i0); float n0 = __int_as_float(__shfl(my.y, i0));
            int   s1 = __shfl(my.x, i1); float n1 = __int_as_float(__shfl(my.y, i1));
            int   s2 = __shfl(my.x, i2); float n2 = __int_as_float(__shfl(my.y, i2));
            int   s3 = __shfl(my.x, i3); float n3 = __int_as_float(__shfl(my.y, i3));
            float4 h0 = h4[(size_t)s0 * 32 + l32];
            float4 h1 = h4[(size_t)s1 * 32 + l32];
            float4 h2 = h4[(size_t)s2 * 32 + l32];
            float4 h3 = h4[(size_t)s3 * 32 + l32];
            acc.x = fmaf(h0.x, n0, acc.x); acc.y = fmaf(h0.y, n0, acc.y);
            acc.z = fmaf(h0.z, n0, acc.z); acc.w = fmaf(h0.w, n0, acc.w);
            acc.x = fmaf(h1.x, n1, acc.x); acc.y = fmaf(h1.y, n1, acc.y);
            acc.z = fmaf(h1.z, n1, acc.z); acc.w = fmaf(h1.w, n1, acc.w);
            acc.x = fmaf(h2.x, n2, acc.x); acc.y = fmaf(h2.y, n2, acc.y);
            acc.z = fmaf(h2.z, n2, acc.z); acc.w = fmaf(h2.w, n2, acc.w);
            acc.x = fmaf(h3.x, n3, acc.x); acc.y = fmaf(h3.y, n3, acc.y);
            acc.z = fmaf(h3.z, n3, acc.z); acc.w = fmaf(h3.w, n3, acc.w);
        }
    }

    // combine the two halves (lane^32)
    acc.x += __shfl_xor(acc.x, 32, 64);
    acc.y += __shfl_xor(acc.y, 32, 64);
    acc.z += __shfl_xor(acc.z, 32, 64);
    acc.w += __shfl_xor(acc.w, 32, 64);

    float dv = dinv[v];
    float ss = dv * dv;
    float4 hv = h4[(size_t)v * 32 + l32];
    float4 bv = ((const float4*)bias)[l32];
    acc.x = fmaf(hv.x, ss, acc.x) + bv.x;
    acc.y = fmaf(hv.y, ss, acc.y) + bv.y;
    acc.z = fmaf(hv.z, ss, acc.z) + bv.z;
    acc.w = fmaf(hv.w, ss, acc.w) + bv.w;
    if (do_relu) {
        acc.x = fmaxf(acc.x, 0.f); acc.y = fmaxf(acc.y, 0.f);
        acc.z = fmaxf(acc.z, 0.f); acc.w = fmaxf(acc.w, 0.f);
    }
    if (half == 0) ((float4*)z)[(size_t)v * 32 + l32] = acc;
}

// Two label edges per wave (one per half-wave): out[e] = dot(z[s], z[d]).
__global__ __launch_bounds__(256) void decode_kern(const int* __restrict__ s_idx,
                                                   const int* __restrict__ d_idx,
                                                   const float* __restrict__ z,
                                                   float* __restrict__ out, int EL) {
    int lane = threadIdx.x & (WAVE - 1);
    int wave = (blockIdx.x * blockDim.x + threadIdx.x) >> 6;
    int half = lane >> 5;
    int l32 = lane & 31;
    int e = wave * 2 + half;
    if (e >= EL) return;
    int s = s_idx[e];
    int d = d_idx[e];
    const float4* z4 = (const float4*)z;
    float4 a = z4[(size_t)s * 32 + l32];
    float4 b = z4[(size_t)d * 32 + l32];
    float p = a.x * b.x + a.y * b.y + a.z * b.z + a.w * b.w;
#pragma unroll
    for (int off = 16; off > 0; off >>= 1) p += __shfl_xor(p, off, 64);  // stays in half
    if (l32 == 0) out[e] = p;
}

extern "C" void kernel_launch(void* const* d_in, const int* in_sizes, int n_in,
                              void* d_out, int out_size, void* d_ws, size_t ws_size,
                              hipStream_t stream) {
    const float* x   = (const float*)d_in[0];
    const int*   ei  = (const int*)d_in[1];
    const int*   eli = (const int*)d_in[2];
    const float* W1  = (const float*)d_in[3];
    const float* b1  = (const float*)d_in[4];
    const float* W2  = (const float*)d_in[5];
    const float* b2  = (const float*)d_in[6];
    float* out = (float*)d_out;

    int N  = in_sizes[0] / 128;
    int E  = in_sizes[1] / 2;
    int EL = in_sizes[2] / 2;
    const int* src = ei;
    const int* dst = ei + E;
    const int* ls  = eli;
    const int* ld  = eli + EL;

    char* ws = (char*)d_ws;
    float* dinv    = (float*)(ws);
    int*   deg     = (int*)(ws + (512 << 10));
    int*   row_off = (int*)(ws + (1024 << 10));
    int*   cursor  = (int*)(ws + (1536 << 10));
    int*   bsum    = (int*)(ws + (1984 << 10));
    int2*  csr     = (int2*)(ws + (2048 << 10));
    float* bufH    = (float*)(ws + (16u << 20));
    float* bufZ    = (float*)(ws + (16u << 20) + (size_t)51200000u);

    int nodeGrid = (N + 255) / 256;
    int edgeGrid = (E + 255) / 256;
    int gemmGrid = (N + 63) / 64;
    int aggGrid  = (N + 3) / 4;   // 4 waves/block, 1 wave/node
    int nbScan   = (N + SCAN_CHUNK - 1) / SCAN_CHUNK;  // 98 for N=100K (<=128)

    // CSR build (shared by both layers)
    zero2_kern<<<nodeGrid, 256, 0, stream>>>(deg, cursor, N);
    deg_count_kern<<<edgeGrid, 256, 0, stream>>>(dst, deg, E);
    scan_part_kern<<<nbScan, 256, 0, stream>>>(deg, bsum, N);
    scan_top_kern<<<1, 128, 0, stream>>>(bsum, row_off, nbScan, N);
    scan_apply_kern<<<nbScan, 256, 0, stream>>>(deg, bsum, row_off, dinv, N);
    fill_kern<<<edgeGrid, 256, 0, stream>>>(src, dst, row_off, cursor, dinv, csr, E);

    // layer 1
    gemm128_kern<<<gemmGrid, 256, 0, stream>>>(x, W1, bufH, N);
    agg_kern<<<aggGrid, 256, 0, stream>>>(row_off, csr, dinv, bufH, b1, bufZ, N, 1);

    // layer 2
    gemm128_kern<<<gemmGrid, 256, 0, stream>>>(bufZ, W2, bufH, N);
    agg_kern<<<aggGrid, 256, 0, stream>>>(row_off, csr, dinv, bufH, b2, bufZ, N, 0);

    // decode: 2 edges per wave
    decode_kern<<<(EL + 7) / 8, 256, 0, stream>>>(ls, ld, bufZ, out, EL);
}

// Round 5
// 594.304 us; speedup vs baseline: 5.1274x; 1.0221x over previous
//
#include <hip/hip_runtime.h>
#include <hip/hip_bf16.h>
#include <math.h>

// GCN link predictor: N=100000 nodes, d=128, E=1.6M edges, EL=200K label edges.
// Round 5: agg_kern was latency-bound (VGPR_Count=24 => compiler serialized
// gathers, ~2 outstanding loads/wave, beyond-L2 BW stuck at 3.3 TB/s despite
// L3-resident working set). Restructure: 16-edge chunks, shfl all indices
// first, 8 independent half-split float4 gathers into explicit arrays, then
// FMAs. decode: 4 edges/wave, 4 independent loads.
//
// Workspace layout (bytes):
//   0        dinv    float[N]     (400 KB)
//   512K     deg     int[N]       (400 KB)
//   1024K    row_off int[N+1]     (400 KB)
//   1536K    cursor  int[N]       (400 KB)
//   1984K    bsum    int[128]
//   2048K    csr     int2[E]      (12.8 MB)
//   16M      bufH    float[N*128] (51.2 MB)
//   16M+51.2M bufZ   float[N*128] (51.2 MB)   total ~113.7 MiB

#define WAVE 64
#define SCAN_CHUNK 1024   // elements per block (256 threads x 4)
#define GK 32             // gemm k-chunk

__global__ __launch_bounds__(256) void zero2_kern(int* __restrict__ a,
                                                  int* __restrict__ b, int N) {
    int i = blockIdx.x * blockDim.x + threadIdx.x;
    if (i < N) { a[i] = 0; b[i] = 0; }
}

__global__ __launch_bounds__(256) void deg_count_kern(const int* __restrict__ dst,
                                                      int* __restrict__ deg, int E) {
    int i = blockIdx.x * blockDim.x + threadIdx.x;
    if (i < E) atomicAdd(&deg[dst[i]], 1);
}

__device__ __forceinline__ int load4_sum(const int* __restrict__ deg, int base, int N,
                                         int4* out) {
    int4 v = make_int4(0, 0, 0, 0);
    if (base + 3 < N) {
        v = ((const int4*)deg)[base >> 2];
    } else {
        if (base + 0 < N) v.x = deg[base + 0];
        if (base + 1 < N) v.y = deg[base + 1];
        if (base + 2 < N) v.z = deg[base + 2];
        if (base + 3 < N) v.w = deg[base + 3];
    }
    *out = v;
    return v.x + v.y + v.z + v.w;
}

// Per-block partial sums of deg.
__global__ __launch_bounds__(256) void scan_part_kern(const int* __restrict__ deg,
                                                      int* __restrict__ bsum, int N) {
    __shared__ int sdata[256];
    int t = threadIdx.x;
    int base = blockIdx.x * SCAN_CHUNK + t * 4;
    int4 v;
    int sum = load4_sum(deg, base, N, &v);
    sdata[t] = sum;
    __syncthreads();
#pragma unroll
    for (int off = 128; off > 0; off >>= 1) {
        if (t < off) sdata[t] += sdata[t + off];
        __syncthreads();
    }
    if (t == 0) bsum[blockIdx.x] = sdata[0];
}

// Single small block: exclusive scan of nb (<=128) block sums; row_off[N]=total.
__global__ __launch_bounds__(128) void scan_top_kern(int* __restrict__ bsum,
                                                     int* __restrict__ row_off,
                                                     int nb, int N) {
    __shared__ int sdata[128];
    int t = threadIdx.x;
    int own = (t < nb) ? bsum[t] : 0;
    sdata[t] = own;
    __syncthreads();
#pragma unroll
    for (int off = 1; off < 128; off <<= 1) {
        int v = sdata[t];
        int add = (t >= off) ? sdata[t - off] : 0;
        __syncthreads();
        sdata[t] = v + add;
        __syncthreads();
    }
    if (t < nb) bsum[t] = sdata[t] - own;   // exclusive
    if (t == 127) row_off[N] = sdata[127];  // total == E
}

// Re-scan locally, add block offset, write row_off + dinv.
__global__ __launch_bounds__(256) void scan_apply_kern(const int* __restrict__ deg,
                                                       const int* __restrict__ bsum,
                                                       int* __restrict__ row_off,
                                                       float* __restrict__ dinv, int N) {
    __shared__ int sdata[256];
    int t = threadIdx.x;
    int base = blockIdx.x * SCAN_CHUNK + t * 4;
    int4 v;
    int sum = load4_sum(deg, base, N, &v);
    sdata[t] = sum;
    __syncthreads();
#pragma unroll
    for (int off = 1; off < 256; off <<= 1) {
        int x = sdata[t];
        int add = (t >= off) ? sdata[t - off] : 0;
        __syncthreads();
        sdata[t] = x + add;
        __syncthreads();
    }
    int run = bsum[blockIdx.x] + sdata[t] - sum;  // global exclusive prefix
    if (base + 0 < N) { row_off[base + 0] = run; dinv[base + 0] = rsqrtf((float)(v.x + 1)); run += v.x; }
    if (base + 1 < N) { row_off[base + 1] = run; dinv[base + 1] = rsqrtf((float)(v.y + 1)); run += v.y; }
    if (base + 2 < N) { row_off[base + 2] = run; dinv[base + 2] = rsqrtf((float)(v.z + 1)); run += v.z; }
    if (base + 3 < N) { row_off[base + 3] = run; dinv[base + 3] = rsqrtf((float)(v.w + 1)); }
}

// csr[row_off[dst]+slot] = {src, norm}.
__global__ __launch_bounds__(256) void fill_kern(const int* __restrict__ src,
                                                 const int* __restrict__ dst,
                                                 const int* __restrict__ row_off,
                                                 int* __restrict__ cursor,
                                                 const float* __restrict__ dinv,
                                                 int2* __restrict__ csr, int E) {
    int e = blockIdx.x * blockDim.x + threadIdx.x;
    if (e >= E) return;
    int s = src[e], d = dst[e];
    int p = atomicAdd(&cursor[d], 1);
    int2 v;
    v.x = s;
    v.y = __float_as_int(dinv[s] * dinv[d]);
    csr[row_off[d] + p] = v;
}

// H[M,128] = X[M,128] @ W[128,128], fp32. One block: 64 rows x 128 cols.
// K chunked by GK=32: LDS = 24 KB -> 6 blocks/CU.
__global__ __launch_bounds__(256) void gemm128_kern(const float* __restrict__ X,
                                                    const float* __restrict__ W,
                                                    float* __restrict__ H, int M) {
    __shared__ float xs[64][GK];      // 8 KB
    __shared__ float wsm[GK][128];    // 16 KB
    int tid = threadIdx.x;
    int block_row = blockIdx.x * 64;
    int tx = tid & 31;
    int ty = tid >> 5;

    float4 acc[8];
#pragma unroll
    for (int i = 0; i < 8; ++i) acc[i] = make_float4(0.f, 0.f, 0.f, 0.f);

    for (int k0 = 0; k0 < 128; k0 += GK) {
        __syncthreads();  // protect previous chunk's LDS reads
        {
            const float4* W4 = (const float4*)(W + (size_t)k0 * 128);
            float4* w4 = (float4*)wsm;
#pragma unroll
            for (int i = 0; i < 4; ++i) w4[tid + 256 * i] = W4[tid + 256 * i];
        }
        {
#pragma unroll
            for (int i = 0; i < 2; ++i) {
                int idx = tid + 256 * i;   // 0..511
                int r = idx >> 3;          // 0..63
                int c = idx & 7;           // float4 within chunk
                int grow = block_row + r;
                float4 v = make_float4(0.f, 0.f, 0.f, 0.f);
                if (grow < M) v = ((const float4*)X)[(size_t)grow * 32 + (k0 >> 2) + c];
                ((float4*)xs)[idx] = v;
            }
        }
        __syncthreads();

#pragma unroll 4
        for (int kk = 0; kk < GK; ++kk) {
            float4 wv = ((float4*)&wsm[kk][0])[tx];
            float xr[8];
#pragma unroll
            for (int i = 0; i < 8; ++i) xr[i] = xs[ty * 8 + i][kk];
#pragma unroll
            for (int i = 0; i < 8; ++i) {
                acc[i].x = fmaf(xr[i], wv.x, acc[i].x);
                acc[i].y = fmaf(xr[i], wv.y, acc[i].y);
                acc[i].z = fmaf(xr[i], wv.z, acc[i].z);
                acc[i].w = fmaf(xr[i], wv.w, acc[i].w);
            }
        }
    }

#pragma unroll
    for (int i = 0; i < 8; ++i) {
        int grow = block_row + ty * 8 + i;
        if (grow < M) ((float4*)H)[(size_t)grow * 32 + tx] = acc[i];
    }
}

// One wave per node. 16-edge chunks: shfl all {src,norm}, issue 8 independent
// half-split float4 gathers (lanes 0-31 = even slot row, 32-63 = odd slot row),
// then FMAs. Tail slots padded with (s=0, n=0): row-0 load is cache-hot, *0 fma.
// z[v] = (relu?)(sum_{s in N(v)} h[s]*norm + h[v]*dinv^2 + b)
__global__ __launch_bounds__(256) void agg_kern(const int* __restrict__ row_off,
                                                const int2* __restrict__ csr,
                                                const float* __restrict__ dinv,
                                                const float* __restrict__ h,
                                                const float* __restrict__ bias,
                                                float* __restrict__ z,
                                                int N, int do_relu) {
    int wave = (blockIdx.x * blockDim.x + threadIdx.x) >> 6;
    int lane = threadIdx.x & (WAVE - 1);
    if (wave >= N) return;
    int v = wave;
    int half = lane >> 5;    // lanes 0-31: even edge slots, 32-63: odd slots
    int l32 = lane & 31;
    int beg = row_off[v];
    int degv = row_off[v + 1] - beg;
    const float4* h4 = (const float4*)h;

    float4 acc = make_float4(0.f, 0.f, 0.f, 0.f);

    for (int base = 0; base < degv; base += WAVE) {
        int cnt = degv - base; if (cnt > WAVE) cnt = WAVE;
        int2 my = make_int2(0, 0);  // lanes >= cnt hold (s=0, n=0)
        if (lane < cnt) my = csr[beg + base + lane];
        for (int j = 0; j < cnt; j += 16) {
            int   sidx[8];
            float nn[8];
#pragma unroll
            for (int u = 0; u < 8; ++u) {
                int sl = j + 2 * u + half;              // slot in [j, j+16)
                sidx[u] = __shfl(my.x, sl);
                nn[u]   = __int_as_float(__shfl(my.y, sl));
            }
            float4 hv[8];
#pragma unroll
            for (int u = 0; u < 8; ++u)                 // 8 independent 1 KB gathers
                hv[u] = h4[(size_t)sidx[u] * 32 + l32];
#pragma unroll
            for (int u = 0; u < 8; ++u) {
                acc.x = fmaf(hv[u].x, nn[u], acc.x);
                acc.y = fmaf(hv[u].y, nn[u], acc.y);
                acc.z = fmaf(hv[u].z, nn[u], acc.z);
                acc.w = fmaf(hv[u].w, nn[u], acc.w);
            }
        }
    }

    // combine the two halves (lane^32)
    acc.x += __shfl_xor(acc.x, 32, 64);
    acc.y += __shfl_xor(acc.y, 32, 64);
    acc.z += __shfl_xor(acc.z, 32, 64);
    acc.w += __shfl_xor(acc.w, 32, 64);

    float dv = dinv[v];
    float ss = dv * dv;
    float4 hv = h4[(size_t)v * 32 + l32];
    float4 bv = ((const float4*)bias)[l32];
    acc.x = fmaf(hv.x, ss, acc.x) + bv.x;
    acc.y = fmaf(hv.y, ss, acc.y) + bv.y;
    acc.z = fmaf(hv.z, ss, acc.z) + bv.z;
    acc.w = fmaf(hv.w, ss, acc.w) + bv.w;
    if (do_relu) {
        acc.x = fmaxf(acc.x, 0.f); acc.y = fmaxf(acc.y, 0.f);
        acc.z = fmaxf(acc.z, 0.f); acc.w = fmaxf(acc.w, 0.f);
    }
    if (half == 0) ((float4*)z)[(size_t)v * 32 + l32] = acc;
}

// Four label edges per wave (2 per half-wave), 4 independent row loads in
// flight: out[e] = dot(z[s], z[d]).
__global__ __launch_bounds__(256) void decode_kern(const int* __restrict__ s_idx,
                                                   const int* __restrict__ d_idx,
                                                   const float* __restrict__ z,
                                                   float* __restrict__ out, int EL) {
    int lane = threadIdx.x & (WAVE - 1);
    int wave = (blockIdx.x * blockDim.x + threadIdx.x) >> 6;
    int half = lane >> 5;
    int l32 = lane & 31;
    int e0 = wave * 4 + half;      // this half-wave handles e0 and e0+2
    int e1 = e0 + 2;
    const float4* z4 = (const float4*)z;

    int s0 = 0, d0 = 0, s1 = 0, d1 = 0;
    if (e0 < EL) { s0 = s_idx[e0]; d0 = d_idx[e0]; }
    if (e1 < EL) { s1 = s_idx[e1]; d1 = d_idx[e1]; }
    float4 a0 = z4[(size_t)s0 * 32 + l32];
    float4 b0 = z4[(size_t)d0 * 32 + l32];
    float4 a1 = z4[(size_t)s1 * 32 + l32];
    float4 b1 = z4[(size_t)d1 * 32 + l32];
    float p0 = a0.x * b0.x + a0.y * b0.y + a0.z * b0.z + a0.w * b0.w;
    float p1 = a1.x * b1.x + a1.y * b1.y + a1.z * b1.z + a1.w * b1.w;
#pragma unroll
    for (int off = 16; off > 0; off >>= 1) {
        p0 += __shfl_xor(p0, off, 64);   // stays within the 32-lane half
        p1 += __shfl_xor(p1, off, 64);
    }
    if (l32 == 0) {
        if (e0 < EL) out[e0] = p0;
        if (e1 < EL) out[e1] = p1;
    }
}

extern "C" void kernel_launch(void* const* d_in, const int* in_sizes, int n_in,
                              void* d_out, int out_size, void* d_ws, size_t ws_size,
                              hipStream_t stream) {
    const float* x   = (const float*)d_in[0];
    const int*   ei  = (const int*)d_in[1];
    const int*   eli = (const int*)d_in[2];
    const float* W1  = (const float*)d_in[3];
    const float* b1  = (const float*)d_in[4];
    const float* W2  = (const float*)d_in[5];
    const float* b2  = (const float*)d_in[6];
    float* out = (float*)d_out;

    int N  = in_sizes[0] / 128;
    int E  = in_sizes[1] / 2;
    int EL = in_sizes[2] / 2;
    const int* src = ei;
    const int* dst = ei + E;
    const int* ls  = eli;
    const int* ld  = eli + EL;

    char* ws = (char*)d_ws;
    float* dinv    = (float*)(ws);
    int*   deg     = (int*)(ws + (512 << 10));
    int*   row_off = (int*)(ws + (1024 << 10));
    int*   cursor  = (int*)(ws + (1536 << 10));
    int*   bsum    = (int*)(ws + (1984 << 10));
    int2*  csr     = (int2*)(ws + (2048 << 10));
    float* bufH    = (float*)(ws + (16u << 20));
    float* bufZ    = (float*)(ws + (16u << 20) + (size_t)51200000u);

    int nodeGrid = (N + 255) / 256;
    int edgeGrid = (E + 255) / 256;
    int gemmGrid = (N + 63) / 64;
    int aggGrid  = (N + 3) / 4;   // 4 waves/block, 1 wave/node
    int nbScan   = (N + SCAN_CHUNK - 1) / SCAN_CHUNK;  // 98 for N=100K (<=128)

    // CSR build (shared by both layers)
    zero2_kern<<<nodeGrid, 256, 0, stream>>>(deg, cursor, N);
    deg_count_kern<<<edgeGrid, 256, 0, stream>>>(dst, deg, E);
    scan_part_kern<<<nbScan, 256, 0, stream>>>(deg, bsum, N);
    scan_top_kern<<<1, 128, 0, stream>>>(bsum, row_off, nbScan, N);
    scan_apply_kern<<<nbScan, 256, 0, stream>>>(deg, bsum, row_off, dinv, N);
    fill_kern<<<edgeGrid, 256, 0, stream>>>(src, dst, row_off, cursor, dinv, csr, E);

    // layer 1
    gemm128_kern<<<gemmGrid, 256, 0, stream>>>(x, W1, bufH, N);
    agg_kern<<<aggGrid, 256, 0, stream>>>(row_off, csr, dinv, bufH, b1, bufZ, N, 1);

    // layer 2
    gemm128_kern<<<gemmGrid, 256, 0, stream>>>(bufZ, W2, bufH, N);
    agg_kern<<<aggGrid, 256, 0, stream>>>(row_off, csr, dinv, bufH, b2, bufZ, N, 0);

    // decode: 4 edges per wave
    decode_kern<<<(EL + 15) / 16, 256, 0, stream>>>(ls, ld, bufZ, out, EL);
}

// Round 6
// 508.287 us; speedup vs baseline: 5.9951x; 1.1692x over previous
//
#include <hip/hip_runtime.h>
#include <hip/hip_bf16.h>
#include <math.h>

// GCN link predictor: N=100000 nodes, d=128, E=1.6M edges, EL=200K label edges.
// Round 6: agg is L2-fill-path BW-bound: FETCH_SIZE=404MB == 8 XCDs x 51MB
// (every XCD's private L2 fetches the whole randomly-gathered h array);
// ~3.9 TB/s sustained on that path across 3 structurally different inner
// loops. Attack the BYTES: h1/h2 and z2 stored bf16 (RNE) -> gather demand
// halved; csr slimmed to int{src} with norm recomputed from L2-resident dinv
// (dst factor is wave-uniform). z1 stays fp32 (streamed only, no gather).
//
// Workspace layout (bytes):
//   0        dinv    float[N]      (400 KB)
//   512K     deg     int[N]        (400 KB)
//   1024K    row_off int[N+1]      (400 KB)
//   1536K    cursor  int[N]        (400 KB)
//   1984K    bsum    int[128]
//   2048K    csr     int[E]        (6.4 MB)
//   16M      hbuf    bf16[N*128]   (25.6 MB)  h1, then h2 (overwritten)
//   48M      zbuf    float[N*128]  (51.2 MB)  z1 fp32, then z2 bf16 (reuse)
//   total ~93 MiB

#define WAVE 64
#define SCAN_CHUNK 1024   // elements per block (256 threads x 4)
#define GK 32             // gemm k-chunk

// ---- bf16 pack/unpack (RNE) ----
__device__ __forceinline__ unsigned bf16_rne(float f) {
    unsigned u = __float_as_uint(f);
    return (u + 0x7FFFu + ((u >> 16) & 1u)) >> 16;
}
__device__ __forceinline__ uint2 pack4_bf16(float4 v) {
    uint2 o;
    o.x = bf16_rne(v.x) | (bf16_rne(v.y) << 16);
    o.y = bf16_rne(v.z) | (bf16_rne(v.w) << 16);
    return o;
}
__device__ __forceinline__ float4 unpack4_bf16(uint2 p) {
    float4 o;
    o.x = __uint_as_float(p.x << 16);
    o.y = __uint_as_float(p.x & 0xFFFF0000u);
    o.z = __uint_as_float(p.y << 16);
    o.w = __uint_as_float(p.y & 0xFFFF0000u);
    return o;
}

__global__ __launch_bounds__(256) void zero2_kern(int* __restrict__ a,
                                                  int* __restrict__ b, int N) {
    int i = blockIdx.x * blockDim.x + threadIdx.x;
    if (i < N) { a[i] = 0; b[i] = 0; }
}

__global__ __launch_bounds__(256) void deg_count_kern(const int* __restrict__ dst,
                                                      int* __restrict__ deg, int E) {
    int i = blockIdx.x * blockDim.x + threadIdx.x;
    if (i < E) atomicAdd(&deg[dst[i]], 1);
}

__device__ __forceinline__ int load4_sum(const int* __restrict__ deg, int base, int N,
                                         int4* out) {
    int4 v = make_int4(0, 0, 0, 0);
    if (base + 3 < N) {
        v = ((const int4*)deg)[base >> 2];
    } else {
        if (base + 0 < N) v.x = deg[base + 0];
        if (base + 1 < N) v.y = deg[base + 1];
        if (base + 2 < N) v.z = deg[base + 2];
        if (base + 3 < N) v.w = deg[base + 3];
    }
    *out = v;
    return v.x + v.y + v.z + v.w;
}

// Per-block partial sums of deg.
__global__ __launch_bounds__(256) void scan_part_kern(const int* __restrict__ deg,
                                                      int* __restrict__ bsum, int N) {
    __shared__ int sdata[256];
    int t = threadIdx.x;
    int base = blockIdx.x * SCAN_CHUNK + t * 4;
    int4 v;
    int sum = load4_sum(deg, base, N, &v);
    sdata[t] = sum;
    __syncthreads();
#pragma unroll
    for (int off = 128; off > 0; off >>= 1) {
        if (t < off) sdata[t] += sdata[t + off];
        __syncthreads();
    }
    if (t == 0) bsum[blockIdx.x] = sdata[0];
}

// Single small block: exclusive scan of nb (<=128) block sums; row_off[N]=total.
__global__ __launch_bounds__(128) void scan_top_kern(int* __restrict__ bsum,
                                                     int* __restrict__ row_off,
                                                     int nb, int N) {
    __shared__ int sdata[128];
    int t = threadIdx.x;
    int own = (t < nb) ? bsum[t] : 0;
    sdata[t] = own;
    __syncthreads();
#pragma unroll
    for (int off = 1; off < 128; off <<= 1) {
        int v = sdata[t];
        int add = (t >= off) ? sdata[t - off] : 0;
        __syncthreads();
        sdata[t] = v + add;
        __syncthreads();
    }
    if (t < nb) bsum[t] = sdata[t] - own;   // exclusive
    if (t == 127) row_off[N] = sdata[127];  // total == E
}

// Re-scan locally, add block offset, write row_off + dinv.
__global__ __launch_bounds__(256) void scan_apply_kern(const int* __restrict__ deg,
                                                       const int* __restrict__ bsum,
                                                       int* __restrict__ row_off,
                                                       float* __restrict__ dinv, int N) {
    __shared__ int sdata[256];
    int t = threadIdx.x;
    int base = blockIdx.x * SCAN_CHUNK + t * 4;
    int4 v;
    int sum = load4_sum(deg, base, N, &v);
    sdata[t] = sum;
    __syncthreads();
#pragma unroll
    for (int off = 1; off < 256; off <<= 1) {
        int x = sdata[t];
        int add = (t >= off) ? sdata[t - off] : 0;
        __syncthreads();
        sdata[t] = x + add;
        __syncthreads();
    }
    int run = bsum[blockIdx.x] + sdata[t] - sum;  // global exclusive prefix
    if (base + 0 < N) { row_off[base + 0] = run; dinv[base + 0] = rsqrtf((float)(v.x + 1)); run += v.x; }
    if (base + 1 < N) { row_off[base + 1] = run; dinv[base + 1] = rsqrtf((float)(v.y + 1)); run += v.y; }
    if (base + 2 < N) { row_off[base + 2] = run; dinv[base + 2] = rsqrtf((float)(v.z + 1)); run += v.z; }
    if (base + 3 < N) { row_off[base + 3] = run; dinv[base + 3] = rsqrtf((float)(v.w + 1)); }
}

// csr[row_off[dst]+slot] = src  (norm recomputed in agg from dinv).
__global__ __launch_bounds__(256) void fill_kern(const int* __restrict__ src,
                                                 const int* __restrict__ dst,
                                                 const int* __restrict__ row_off,
                                                 int* __restrict__ cursor,
                                                 int* __restrict__ csr, int E) {
    int e = blockIdx.x * blockDim.x + threadIdx.x;
    if (e >= E) return;
    int d = dst[e];
    int p = atomicAdd(&cursor[d], 1);
    csr[row_off[d] + p] = src[e];
}

// H[M,128](bf16) = X[M,128](fp32) @ W[128,128](fp32). 64 rows x 128 cols/block.
// K chunked by GK=32: LDS = 24 KB -> 6 blocks/CU.
__global__ __launch_bounds__(256) void gemm128_kern(const float* __restrict__ X,
                                                    const float* __restrict__ W,
                                                    uint2* __restrict__ H16, int M) {
    __shared__ float xs[64][GK];      // 8 KB
    __shared__ float wsm[GK][128];    // 16 KB
    int tid = threadIdx.x;
    int block_row = blockIdx.x * 64;
    int tx = tid & 31;
    int ty = tid >> 5;

    float4 acc[8];
#pragma unroll
    for (int i = 0; i < 8; ++i) acc[i] = make_float4(0.f, 0.f, 0.f, 0.f);

    for (int k0 = 0; k0 < 128; k0 += GK) {
        __syncthreads();  // protect previous chunk's LDS reads
        {
            const float4* W4 = (const float4*)(W + (size_t)k0 * 128);
            float4* w4 = (float4*)wsm;
#pragma unroll
            for (int i = 0; i < 4; ++i) w4[tid + 256 * i] = W4[tid + 256 * i];
        }
        {
#pragma unroll
            for (int i = 0; i < 2; ++i) {
                int idx = tid + 256 * i;   // 0..511
                int r = idx >> 3;          // 0..63
                int c = idx & 7;           // float4 within chunk
                int grow = block_row + r;
                float4 v = make_float4(0.f, 0.f, 0.f, 0.f);
                if (grow < M) v = ((const float4*)X)[(size_t)grow * 32 + (k0 >> 2) + c];
                ((float4*)xs)[idx] = v;
            }
        }
        __syncthreads();

#pragma unroll 4
        for (int kk = 0; kk < GK; ++kk) {
            float4 wv = ((float4*)&wsm[kk][0])[tx];
            float xr[8];
#pragma unroll
            for (int i = 0; i < 8; ++i) xr[i] = xs[ty * 8 + i][kk];
#pragma unroll
            for (int i = 0; i < 8; ++i) {
                acc[i].x = fmaf(xr[i], wv.x, acc[i].x);
                acc[i].y = fmaf(xr[i], wv.y, acc[i].y);
                acc[i].z = fmaf(xr[i], wv.z, acc[i].z);
                acc[i].w = fmaf(xr[i], wv.w, acc[i].w);
            }
        }
    }

#pragma unroll
    for (int i = 0; i < 8; ++i) {
        int grow = block_row + ty * 8 + i;
        if (grow < M) H16[(size_t)grow * 32 + tx] = pack4_bf16(acc[i]);
    }
}

// One wave per node, h in bf16 (256 B rows). 16-edge chunks: per-lane load
// src + dinv[src] (L2-resident 400 KB), shfl {src, norm}, 8 independent
// half-split uint2 gathers (1 load = 2 edge rows), unpack + FMA.
// z[v] = (relu?)(sum h[s]*dinv[s]*dinv[v] + h[v]*dinv[v]^2 + b)
// out_bf16: write z packed bf16 (uint2/lane) else fp32 (float4/lane).
__global__ __launch_bounds__(256) void agg_kern(const int* __restrict__ row_off,
                                                const int* __restrict__ csr,
                                                const float* __restrict__ dinv,
                                                const uint2* __restrict__ h16,
                                                const float* __restrict__ bias,
                                                void* __restrict__ z,
                                                int N, int do_relu, int out_bf16) {
    int wave = (blockIdx.x * blockDim.x + threadIdx.x) >> 6;
    int lane = threadIdx.x & (WAVE - 1);
    if (wave >= N) return;
    int v = wave;
    int half = lane >> 5;    // lanes 0-31: even edge slots, 32-63: odd slots
    int l32 = lane & 31;
    int beg = row_off[v];
    int degv = row_off[v + 1] - beg;
    float dv = dinv[v];

    float4 acc = make_float4(0.f, 0.f, 0.f, 0.f);

    for (int base = 0; base < degv; base += WAVE) {
        int cnt = degv - base; if (cnt > WAVE) cnt = WAVE;
        int s_lane = 0;
        float n_lane = 0.f;
        if (lane < cnt) {
            s_lane = csr[beg + base + lane];       // coalesced
            n_lane = dinv[s_lane] * dv;            // dinv: 400 KB, L2-resident
        }
        for (int j = 0; j < cnt; j += 16) {
            int   sidx[8];
            float nn[8];
#pragma unroll
            for (int u = 0; u < 8; ++u) {
                int sl = j + 2 * u + half;          // slot in [j, j+16)
                sidx[u] = __shfl(s_lane, sl);
                nn[u]   = __shfl(n_lane, sl);
            }
            uint2 hv[8];
#pragma unroll
            for (int u = 0; u < 8; ++u)             // 8 independent 512 B gathers
                hv[u] = h16[(size_t)sidx[u] * 32 + l32];
#pragma unroll
            for (int u = 0; u < 8; ++u) {
                float4 f = unpack4_bf16(hv[u]);
                acc.x = fmaf(f.x, nn[u], acc.x);
                acc.y = fmaf(f.y, nn[u], acc.y);
                acc.z = fmaf(f.z, nn[u], acc.z);
                acc.w = fmaf(f.w, nn[u], acc.w);
            }
        }
    }

    // combine the two halves (lane^32)
    acc.x += __shfl_xor(acc.x, 32, 64);
    acc.y += __shfl_xor(acc.y, 32, 64);
    acc.z += __shfl_xor(acc.z, 32, 64);
    acc.w += __shfl_xor(acc.w, 32, 64);

    float ss = dv * dv;
    float4 hv = unpack4_bf16(h16[(size_t)v * 32 + l32]);
    float4 bv = ((const float4*)bias)[l32];
    acc.x = fmaf(hv.x, ss, acc.x) + bv.x;
    acc.y = fmaf(hv.y, ss, acc.y) + bv.y;
    acc.z = fmaf(hv.z, ss, acc.z) + bv.z;
    acc.w = fmaf(hv.w, ss, acc.w) + bv.w;
    if (do_relu) {
        acc.x = fmaxf(acc.x, 0.f); acc.y = fmaxf(acc.y, 0.f);
        acc.z = fmaxf(acc.z, 0.f); acc.w = fmaxf(acc.w, 0.f);
    }
    if (half == 0) {
        if (out_bf16) ((uint2*)z)[(size_t)v * 32 + l32] = pack4_bf16(acc);
        else          ((float4*)z)[(size_t)v * 32 + l32] = acc;
    }
}

// Four label edges per wave (2 per half-wave), z2 in bf16 (256 B rows):
// out[e] = dot(z[s], z[d]).
__global__ __launch_bounds__(256) void decode_kern(const int* __restrict__ s_idx,
                                                   const int* __restrict__ d_idx,
                                                   const uint2* __restrict__ z16,
                                                   float* __restrict__ out, int EL) {
    int lane = threadIdx.x & (WAVE - 1);
    int wave = (blockIdx.x * blockDim.x + threadIdx.x) >> 6;
    int half = lane >> 5;
    int l32 = lane & 31;
    int e0 = wave * 4 + half;      // this half-wave handles e0 and e0+2
    int e1 = e0 + 2;

    int s0 = 0, d0 = 0, s1 = 0, d1 = 0;
    if (e0 < EL) { s0 = s_idx[e0]; d0 = d_idx[e0]; }
    if (e1 < EL) { s1 = s_idx[e1]; d1 = d_idx[e1]; }
    uint2 pa0 = z16[(size_t)s0 * 32 + l32];
    uint2 pb0 = z16[(size_t)d0 * 32 + l32];
    uint2 pa1 = z16[(size_t)s1 * 32 + l32];
    uint2 pb1 = z16[(size_t)d1 * 32 + l32];
    float4 a0 = unpack4_bf16(pa0), b0 = unpack4_bf16(pb0);
    float4 a1 = unpack4_bf16(pa1), b1 = unpack4_bf16(pb1);
    float p0 = a0.x * b0.x + a0.y * b0.y + a0.z * b0.z + a0.w * b0.w;
    float p1 = a1.x * b1.x + a1.y * b1.y + a1.z * b1.z + a1.w * b1.w;
#pragma unroll
    for (int off = 16; off > 0; off >>= 1) {
        p0 += __shfl_xor(p0, off, 64);   // stays within the 32-lane half
        p1 += __shfl_xor(p1, off, 64);
    }
    if (l32 == 0) {
        if (e0 < EL) out[e0] = p0;
        if (e1 < EL) out[e1] = p1;
    }
}

extern "C" void kernel_launch(void* const* d_in, const int* in_sizes, int n_in,
                              void* d_out, int out_size, void* d_ws, size_t ws_size,
                              hipStream_t stream) {
    const float* x   = (const float*)d_in[0];
    const int*   ei  = (const int*)d_in[1];
    const int*   eli = (const int*)d_in[2];
    const float* W1  = (const float*)d_in[3];
    const float* b1  = (const float*)d_in[4];
    const float* W2  = (const float*)d_in[5];
    const float* b2  = (const float*)d_in[6];
    float* out = (float*)d_out;

    int N  = in_sizes[0] / 128;
    int E  = in_sizes[1] / 2;
    int EL = in_sizes[2] / 2;
    const int* src = ei;
    const int* dst = ei + E;
    const int* ls  = eli;
    const int* ld  = eli + EL;

    char* ws = (char*)d_ws;
    float* dinv    = (float*)(ws);
    int*   deg     = (int*)(ws + (512 << 10));
    int*   row_off = (int*)(ws + (1024 << 10));
    int*   cursor  = (int*)(ws + (1536 << 10));
    int*   bsum    = (int*)(ws + (1984 << 10));
    int*   csr     = (int*)(ws + (2048 << 10));
    uint2* hbuf    = (uint2*)(ws + (16u << 20));   // bf16 h (25.6 MB)
    char*  zraw    = ws + (48u << 20);             // z1 fp32 / z2 bf16 (51.2 MB)
    float* z1      = (float*)zraw;
    uint2* z2      = (uint2*)zraw;

    int nodeGrid = (N + 255) / 256;
    int edgeGrid = (E + 255) / 256;
    int gemmGrid = (N + 63) / 64;
    int aggGrid  = (N + 3) / 4;   // 4 waves/block, 1 wave/node
    int nbScan   = (N + SCAN_CHUNK - 1) / SCAN_CHUNK;  // 98 for N=100K (<=128)

    // CSR build (shared by both layers)
    zero2_kern<<<nodeGrid, 256, 0, stream>>>(deg, cursor, N);
    deg_count_kern<<<edgeGrid, 256, 0, stream>>>(dst, deg, E);
    scan_part_kern<<<nbScan, 256, 0, stream>>>(deg, bsum, N);
    scan_top_kern<<<1, 128, 0, stream>>>(bsum, row_off, nbScan, N);
    scan_apply_kern<<<nbScan, 256, 0, stream>>>(deg, bsum, row_off, dinv, N);
    fill_kern<<<edgeGrid, 256, 0, stream>>>(src, dst, row_off, cursor, csr, E);

    // layer 1: h1(bf16) = x @ W1 ; z1(fp32) = relu(agg(h1) + b1)
    gemm128_kern<<<gemmGrid, 256, 0, stream>>>(x, W1, hbuf, N);
    agg_kern<<<aggGrid, 256, 0, stream>>>(row_off, csr, dinv, hbuf, b1, (void*)z1, N, 1, 0);

    // layer 2: h2(bf16) = z1 @ W2 ; z2(bf16) = agg(h2) + b2
    gemm128_kern<<<gemmGrid, 256, 0, stream>>>(z1, W2, hbuf, N);
    agg_kern<<<aggGrid, 256, 0, stream>>>(row_off, csr, dinv, hbuf, b2, (void*)z2, N, 0, 1);

    // decode: 4 edges per wave, bf16 gathers
    decode_kern<<<(EL + 15) / 16, 256, 0, stream>>>(ls, ld, z2, out, EL);
}